// Round 11
// baseline (511.915 us; speedup 1.0000x reference)
//
#include <hip/hip_runtime.h>
#include <math.h>
#include <stdint.h>
#include <initializer_list>

// GCNModelVAE forward on MI355X — round 9 kernel (3rd submission; rounds 9-10
// benches lost to GPU acquisition timeouts, never executed).
// Round-8 counters: GEMMs grid-limited (512 blocks = 2/CU = 25% occ cap, VALU 52%).
//  - split-K=2 on Q/scores/attnV/H2 (+T2 via ASUM): partial buffers, consumer-side
//    merge in next kernel's A-staging (ASUM) / softmax / spmm2 gather. Grids -> 1024.
//  - zzt_fused reverted to KT=16 core (KT=32 cost 144 VGPR in round 7)
//  - select+cut+find merged (LDS tie table); gather+finalize merged. 17 dispatches.

namespace {

constexpr int NN   = 2048;
constexpr int FIN  = 768;
constexpr int H1D  = 512;
constexpr int H2D  = 256;
constexpr int LCD  = 256;
constexpr int TOPK = 512;
constexpr int TOTE = NN * NN;
constexpr int CAP  = 96;
constexpr int NNQ  = NN * 256;           // one score slice
constexpr unsigned ONEB = 0x3F800000u;   // bits of 1.0f

struct SelState {
  unsigned cnt1, T, r, tieRow, tieRem, Ithr, cTotal, pad;
  double sum1, sum0, labSum, kldSum;
};

struct Slot  { const float* A; const float* A2; const float* B; float* C;
               int lda, ldb, ldc, nshift, act; float scale; };
struct Launch{ Slot s[8]; int zend[8]; };
struct EB { const float* adj[2]; int* cnt[2]; int* col[2]; float* val[2]; };
struct SB { const int* cnt[2]; const int* col[2]; const float* val[2];
            const float* S[2]; const float* S2[2]; float* out[2]; int asum; };

__device__ __forceinline__ float leaky(float v) { return v >= 0.f ? v : 0.01f * v; }

// ------- mega GEMM: 64x64 tile, 4x4 micro, KT=16 dbuf, XCD swizzle, opt A=A1+A2 -------
// Grid %8==0. M%64==0, N%64==0, K%16==0, ld %4==0.
template<int TRANSB, int ASUM>
__global__ __launch_bounds__(256)
void mega_gemm(Launch P, int K)
{
  const int G = gridDim.x;
  const int bid = blockIdx.x;
  const int wg = (bid & 7) * (G >> 3) + (bid >> 3);   // XCD-chunked swizzle
  int z = 0, start = 0;
  #pragma unroll
  for (int i = 0; i < 7; ++i)
    if (wg >= P.zend[i]) { z = i + 1; start = P.zend[i]; }
  Slot sl = P.s[0];
  #pragma unroll
  for (int i = 1; i < 8; ++i) if (z == i) sl = P.s[i];
  const int local = wg - start;
  const int by = local >> sl.nshift;
  const int bx = local & ((1 << sl.nshift) - 1);

  __shared__ float As[2][16][68];
  __shared__ float Bs[2][16][68];
  const int t  = threadIdx.x;
  const int bm = by * 64, bn = bx * 64;
  const int lr = t >> 2, lq = t & 3;
  const int bkr = t >> 4, bnq = t & 15;
  const int tx = t & 15, ty = t >> 4;
  const float* Aptr  = sl.A + (long long)(bm + lr) * sl.lda + lq * 4;
  const float* A2ptr = ASUM ? (sl.A2 + (long long)(bm + lr) * sl.lda + lq * 4) : (const float*)0;
  const float* Bt    = sl.B + (long long)(bn + lr) * sl.ldb + lq * 4;
  const float* Bn    = sl.B + (long long)bkr * sl.ldb + bn + bnq * 4;
  float acc[4][4] = {};
  float4 av, bv;

  auto loadg = [&](int k0) {
    av = *(const float4*)(Aptr + k0);
    if (ASUM) {
      float4 w = *(const float4*)(A2ptr + k0);
      av.x += w.x; av.y += w.y; av.z += w.z; av.w += w.w;
    }
    bv = TRANSB ? *(const float4*)(Bt + k0)
                : *(const float4*)(Bn + (long long)k0 * sl.ldb);
  };
  auto stage = [&](int bf) {
    As[bf][lq*4+0][lr]=av.x; As[bf][lq*4+1][lr]=av.y; As[bf][lq*4+2][lr]=av.z; As[bf][lq*4+3][lr]=av.w;
    if (TRANSB) {
      Bs[bf][lq*4+0][lr]=bv.x; Bs[bf][lq*4+1][lr]=bv.y; Bs[bf][lq*4+2][lr]=bv.z; Bs[bf][lq*4+3][lr]=bv.w;
    } else {
      *(float4*)&Bs[bf][bkr][bnq*4] = bv;
    }
  };
  auto compute = [&](int bf) {
    #pragma unroll
    for (int kk = 0; kk < 16; ++kk) {
      float4 a = *(const float4*)&As[bf][kk][ty*4];
      float4 b = *(const float4*)&Bs[bf][kk][tx*4];
      acc[0][0]+=a.x*b.x; acc[0][1]+=a.x*b.y; acc[0][2]+=a.x*b.z; acc[0][3]+=a.x*b.w;
      acc[1][0]+=a.y*b.x; acc[1][1]+=a.y*b.y; acc[1][2]+=a.y*b.z; acc[1][3]+=a.y*b.w;
      acc[2][0]+=a.z*b.x; acc[2][1]+=a.z*b.y; acc[2][2]+=a.z*b.z; acc[2][3]+=a.z*b.w;
      acc[3][0]+=a.w*b.x; acc[3][1]+=a.w*b.y; acc[3][2]+=a.w*b.z; acc[3][3]+=a.w*b.w;
    }
  };

  loadg(0); stage(0); __syncthreads();
  int cur = 0;
  for (int k0 = 16; k0 < K; k0 += 16) {
    loadg(k0);
    compute(cur);
    stage(cur ^ 1);
    __syncthreads();
    cur ^= 1;
  }
  compute(cur);

  #pragma unroll
  for (int i = 0; i < 4; ++i) {
    float4 v;
    float* vp = &v.x;
    #pragma unroll
    for (int j = 0; j < 4; ++j) {
      float q = acc[i][j] * sl.scale;
      if (sl.act == 1) q = leaky(q);
      else if (sl.act == 2) q = 1.f / (1.f + expf(-q));
      vp[j] = q;
    }
    *(float4*)&sl.C[(long long)(bm + ty*4 + i) * sl.ldc + bn + tx*4] = v;
  }
}

// ---------------- z@zT fused (KT=16): sigmoid + symmetric store + BCE + tie counts ----------------
__global__ __launch_bounds__(256)
void zzt_fused(const float* __restrict__ zv, const float* __restrict__ labels,
               float* __restrict__ radj, SelState* st, unsigned* __restrict__ rowTies)
{
  const int bx = blockIdx.x, by = blockIdx.y;
  if (bx < by) return;
  __shared__ float As[2][16][68];
  __shared__ float Bs[2][16][68];
  __shared__ unsigned rt[64];
  __shared__ float red[256];
  const int t = threadIdx.x;
  if (t < 64) rt[t] = 0;
  const int bm = by * 64, bn = bx * 64;
  const int lr = t >> 2, lq = t & 3;
  const int tx = t & 15, ty = t >> 4;
  const float* Ap = zv + (long long)(bm + lr) * 256 + lq * 4;
  const float* Bp = zv + (long long)(bn + lr) * 256 + lq * 4;
  float acc[4][4] = {};
  float4 a0, b0;

  auto loadg = [&](int k0) {
    a0 = *(const float4*)(Ap + k0);
    b0 = *(const float4*)(Bp + k0);
  };
  auto stage = [&](int bf) {
    As[bf][lq*4+0][lr]=a0.x; As[bf][lq*4+1][lr]=a0.y; As[bf][lq*4+2][lr]=a0.z; As[bf][lq*4+3][lr]=a0.w;
    Bs[bf][lq*4+0][lr]=b0.x; Bs[bf][lq*4+1][lr]=b0.y; Bs[bf][lq*4+2][lr]=b0.z; Bs[bf][lq*4+3][lr]=b0.w;
  };
  auto compute = [&](int bf) {
    #pragma unroll
    for (int kk = 0; kk < 16; ++kk) {
      float4 a = *(const float4*)&As[bf][kk][ty*4];
      float4 b = *(const float4*)&Bs[bf][kk][tx*4];
      acc[0][0]+=a.x*b.x; acc[0][1]+=a.x*b.y; acc[0][2]+=a.x*b.z; acc[0][3]+=a.x*b.w;
      acc[1][0]+=a.y*b.x; acc[1][1]+=a.y*b.y; acc[1][2]+=a.y*b.z; acc[1][3]+=a.y*b.w;
      acc[2][0]+=a.z*b.x; acc[2][1]+=a.z*b.y; acc[2][2]+=a.z*b.z; acc[2][3]+=a.z*b.w;
      acc[3][0]+=a.w*b.x; acc[3][1]+=a.w*b.y; acc[3][2]+=a.w*b.z; acc[3][3]+=a.w*b.w;
    }
  };

  loadg(0); stage(0); __syncthreads();
  int cur = 0;
  for (int k0 = 16; k0 < 256; k0 += 16) {
    loadg(k0);
    compute(cur);
    stage(cur ^ 1);
    __syncthreads();
    cur ^= 1;
  }
  compute(cur);

  float o[4][4];
  #pragma unroll
  for (int i = 0; i < 4; ++i)
    #pragma unroll
    for (int j = 0; j < 4; ++j)
      o[i][j] = 1.f / (1.f + expf(-acc[i][j]));

  #pragma unroll
  for (int i = 0; i < 4; ++i)
    *(float4*)&radj[(long long)(bm + ty*4 + i) * NN + bn + tx*4] =
        make_float4(o[i][0], o[i][1], o[i][2], o[i][3]);
  if (bx > by) {
    #pragma unroll
    for (int j = 0; j < 4; ++j)
      *(float4*)&radj[(long long)(bn + tx*4 + j) * NN + bm + ty*4] =
          make_float4(o[0][j], o[1][j], o[2][j], o[3][j]);
  }

  // BCE + labSum + tie counts (strictly-upper only for ties)
  float s1 = 0.f, s0 = 0.f, slb = 0.f;
  unsigned myc1 = 0;
  unsigned c1row[4] = {0, 0, 0, 0};
  #pragma unroll
  for (int i = 0; i < 4; ++i) {
    const int gr = bm + ty*4 + i;
    float4 lbp = *(const float4*)&labels[(long long)gr * NN + bn + tx*4];
    const float* lp = &lbp.x;
    #pragma unroll
    for (int j = 0; j < 4; ++j) {
      const int gc = bn + tx*4 + j;
      float p = o[i][j];
      float e = expf(-p), l1p = log1pf(e);
      float lb = lp[j];
      s1 += lb * l1p;
      s0 += (1.f - lb) * (p + l1p);
      slb += lb;
      if ((bx > by || gc > gr) && __float_as_uint(p) == ONEB) { c1row[i]++; myc1++; }
    }
  }
  if (bx > by) {
    #pragma unroll
    for (int j = 0; j < 4; ++j) {
      float4 lbm = *(const float4*)&labels[(long long)(bn + tx*4 + j) * NN + bm + ty*4];
      const float* lp = &lbm.x;
      #pragma unroll
      for (int i = 0; i < 4; ++i) {
        float p = o[i][j];
        float e = expf(-p), l1p = log1pf(e);
        float lb = lp[i];
        s1 += lb * l1p;
        s0 += (1.f - lb) * (p + l1p);
        slb += lb;
      }
    }
  }
  #pragma unroll
  for (int i = 0; i < 4; ++i)
    if (c1row[i]) atomicAdd(&rt[ty*4 + i], c1row[i]);

  __syncthreads();
  red[t] = s1; __syncthreads();
  for (int s = 128; s > 0; s >>= 1) { if (t < s) red[t] += red[t + s]; __syncthreads(); }
  if (t == 0) atomicAdd(&st->sum1, (double)red[0]);
  __syncthreads();
  red[t] = s0; __syncthreads();
  for (int s = 128; s > 0; s >>= 1) { if (t < s) red[t] += red[t + s]; __syncthreads(); }
  if (t == 0) atomicAdd(&st->sum0, (double)red[0]);
  __syncthreads();
  red[t] = slb; __syncthreads();
  for (int s = 128; s > 0; s >>= 1) { if (t < s) red[t] += red[t + s]; __syncthreads(); }
  if (t == 0) atomicAdd(&st->labSum, (double)red[0]);
  __syncthreads();
  red[t] = (float)myc1; __syncthreads();
  for (int s = 128; s > 0; s >>= 1) { if (t < s) red[t] += red[t + s]; __syncthreads(); }
  if (t == 0 && red[0] > 0.f) atomicAdd(&st->cnt1, (unsigned)red[0]);
  if (t < 64 && rt[t]) atomicAdd(&rowTies[bm + t], rt[t]);
}

// ---------------- ELL build ----------------
__global__ __launch_bounds__(64)
void build_ell(EB eb)
{
  const int b = blockIdx.y, row = blockIdx.x, lane = threadIdx.x;
  const float* adj = eb.adj[b];
  int base = 0;
  for (int c0 = 0; c0 < NN; c0 += 64) {
    float v = adj[(long long)row * NN + c0 + lane];
    unsigned long long m = __ballot(v != 0.0f);
    if (v != 0.0f) {
      int pos = base + __popcll(m & ((1ull << lane) - 1ull));
      if (pos < CAP) { eb.col[b][row * CAP + pos] = c0 + lane; eb.val[b][row * CAP + pos] = v; }
    }
    base += __popcll(m);
  }
  if (lane == 0) eb.cnt[b][row] = base > CAP ? CAP : base;
}

// ------- batched spMM over 512 cols; optional gather-merge S=leaky(S1+S2) -------
__global__ __launch_bounds__(256)
void spmm_leaky(SB sb)
{
  const int b = blockIdx.y, row = blockIdx.x, t = threadIdx.x;
  __shared__ int   sc[CAP];
  __shared__ float sv[CAP];
  __shared__ int   n;
  if (t == 0) n = sb.cnt[b][row];
  if (t < CAP) { sc[t] = sb.col[b][row * CAP + t]; sv[t] = sb.val[b][row * CAP + t]; }
  __syncthreads();
  const int m = n;
  const float* S  = sb.S[b];
  const float* S2 = sb.S2[b];
  float a0 = 0.f, a1 = 0.f;
  if (sb.asum) {
    for (int i = 0; i < m; ++i) {
      long long off = (long long)sc[i] * 512;
      float v = sv[i];
      a0 += v * leaky(S[off + t]       + S2[off + t]);
      a1 += v * leaky(S[off + t + 256] + S2[off + t + 256]);
    }
  } else {
    for (int i = 0; i < m; ++i) {
      long long off = (long long)sc[i] * 512;
      float v = sv[i];
      a0 += v * S[off + t];
      a1 += v * S[off + t + 256];
    }
  }
  sb.out[b][(long long)row * 512 + t]       = leaky(a0);
  sb.out[b][(long long)row * 512 + t + 256] = leaky(a1);
}

// ------- wave softmax over rows of 256, merging split-K partials (x = p1, in-place) -------
__global__ __launch_bounds__(256)
void softmax256(float* __restrict__ x, const float* __restrict__ p2)
{
  const long long row = blockIdx.x * 4 + (threadIdx.x >> 6);
  const int l = threadIdx.x & 63;
  float4 v = *(float4*)&x[row * 256 + l * 4];
  float4 w = *(const float4*)&p2[row * 256 + l * 4];
  v.x += w.x; v.y += w.y; v.z += w.z; v.w += w.w;
  float m = fmaxf(fmaxf(v.x, v.y), fmaxf(v.z, v.w));
  for (int s = 32; s; s >>= 1) m = fmaxf(m, __shfl_xor(m, s));
  float e0 = expf(v.x - m), e1 = expf(v.y - m), e2 = expf(v.z - m), e3 = expf(v.w - m);
  float sm = e0 + e1 + e2 + e3;
  for (int s = 32; s; s >>= 1) sm += __shfl_xor(sm, s);
  float inv = 1.f / sm;
  *(float4*)&x[row * 256 + l * 4] = make_float4(e0*inv, e1*inv, e2*inv, e3*inv);
}

// ---------------- z = eps*exp(0.5*lv)+mu, fused with KLD row partial ----------------
__global__ __launch_bounds__(256)
void z_kld(const float* __restrict__ eps, const float* __restrict__ mpo,
           const float* __restrict__ mpr, float* __restrict__ z, SelState* st)
{
  __shared__ float red[256];
  const int row = blockIdx.x, c = threadIdx.x;
  float mu = mpo[row * 512 + c], lv = mpo[row * 512 + 256 + c];
  z[row * 256 + c] = eps[row * 256 + c] * expf(0.5f * lv) + mu;
  float mu2 = mpr[row * 512 + c], lv2 = mpr[row * 512 + 256 + c];
  float d = mu2 - mu, dl = lv - lv2;
  red[c] = d * d * expf(-lv2) + expf(dl) - 1.f - dl;
  __syncthreads();
  for (int s = 128; s > 0; s >>= 1) { if (c < s) red[c] += red[c + s]; __syncthreads(); }
  if (c == 0) atomicAdd(&st->kldSum, (double)red[0]);
}

// ------- merged select: threshold (fast path or radix) + tie-row cut + exact column -------
__global__ __launch_bounds__(1024)
void select_all(const float* __restrict__ radj, SelState* st,
                const unsigned* __restrict__ rowTies)
{
  const int tid = threadIdx.x;
  __shared__ unsigned rt[NN];          // per-row tie counts (8 KB)
  __shared__ unsigned hist[256];
  __shared__ unsigned ps[256];
  __shared__ unsigned sT, sR, sRow, sRem;
  __shared__ unsigned prefix_s, rem_s;

  const bool fast = (st->cnt1 >= (unsigned)TOPK);
  if (fast) {
    if (tid == 0) { sT = ONEB; sR = TOPK; }
    for (int r = tid; r < NN; r += 1024) rt[r] = rowTies[r];
    __syncthreads();
  } else {
    unsigned prefix = 0, rem = TOPK;
    for (int pass = 0; pass < 4; ++pass) {
      const int shift = 24 - 8 * pass;
      const unsigned mask = pass ? (0xFFFFFFFFu << (32 - 8 * pass)) : 0u;
      if (tid < 256) hist[tid] = 0;
      __syncthreads();
      for (int idx = tid; idx < TOTE; idx += 1024) {
        int i = idx >> 11, j = idx & 2047;
        if (j <= i) continue;
        unsigned b = __float_as_uint(radj[idx]);
        if ((b & mask) == prefix) atomicAdd(&hist[(b >> shift) & 255], 1u);
      }
      __syncthreads();
      if (tid == 0) {
        unsigned cg = 0;
        for (int bb = 255; bb >= 0; --bb) {
          unsigned c = hist[bb];
          if (cg + c >= rem) { prefix |= ((unsigned)bb) << shift; rem -= cg; break; }
          cg += c;
        }
        prefix_s = prefix; rem_s = rem;
      }
      __syncthreads();
      prefix = prefix_s; rem = rem_s;
    }
    if (tid == 0) { sT = prefix; sR = rem; }
    for (int r = tid; r < NN; r += 1024) rt[r] = 0;
    __syncthreads();
    for (int idx = tid; idx < TOTE; idx += 1024) {
      int i = idx >> 11, j = idx & 2047;
      if (j <= i) continue;
      if (__float_as_uint(radj[idx]) == prefix) atomicAdd(&rt[i], 1u);
    }
    __syncthreads();
  }

  // cut: prefix-scan rt to find row containing the sR-th tie
  unsigned s = 0, loc[8];
  if (tid < 256) {
    for (int i = 0; i < 8; ++i) { loc[i] = rt[tid * 8 + i]; s += loc[i]; }
    ps[tid] = s;
  }
  __syncthreads();
  for (int sh = 1; sh < 256; sh <<= 1) {
    unsigned v = 0;
    if (tid < 256 && tid >= sh) v = ps[tid - sh];
    __syncthreads();
    if (tid < 256 && tid >= sh) ps[tid] += v;
    __syncthreads();
  }
  const unsigned r = sR;
  if (tid < 256) {
    const unsigned exc = ps[tid] - s;
    if (r > exc && r <= ps[tid]) {
      unsigned cum = exc;
      for (int i = 0; i < 8; ++i) {
        if (r <= cum + loc[i]) { sRow = tid * 8 + i; sRem = r - cum; break; }
        cum += loc[i];
      }
    }
  }
  __syncthreads();
  // find exact threshold column within cut row (wave 0, ballot)
  if (tid < 64) {
    const int R = (int)sRow;
    const unsigned rem = sRem, T = sT;
    unsigned base = 0;
    for (int c0 = R + 1; c0 < NN; c0 += 64) {
      const int c = c0 + tid;
      bool f = (c < NN) && (__float_as_uint(radj[(long long)R * NN + c]) == T);
      unsigned long long m = __ballot(f);
      unsigned cnt = (unsigned)__popcll(m);
      if (base + cnt >= rem) {
        if (f) {
          unsigned rank = (unsigned)__popcll(m & ((1ull << tid) - 1ull)) + 1u;
          if (base + rank == rem) st->Ithr = (unsigned)(R * NN + c);
        }
        break;
      }
      base += cnt;
    }
  }
  if (tid == 0) { st->T = sT; st->r = sR; }
}

__global__ __launch_bounds__(256)
void collect_kernel(const float* __restrict__ radj, SelState* st,
                    unsigned* __restrict__ cand_bits, unsigned* __restrict__ cand_idx)
{
  const int row = blockIdx.x;
  const unsigned T = st->T, It = st->Ithr;
  for (int c = row + 1 + threadIdx.x; c < NN; c += 256) {
    int idx = row * NN + c;
    unsigned b = __float_as_uint(radj[idx]);
    if (b > T || (b == T && (unsigned)idx <= It)) {
      unsigned p = atomicAdd(&st->cTotal, 1u);
      if (p < (unsigned)TOPK) { cand_bits[p] = b; cand_idx[p] = (unsigned)idx; }
    }
  }
}

__global__ __launch_bounds__(512)
void rank_sort(const unsigned* __restrict__ cand_bits,
               const unsigned* __restrict__ cand_idx, unsigned* __restrict__ ord)
{
  __shared__ unsigned vb[512], vi[512];
  const int t = threadIdx.x;
  vb[t] = cand_bits[t]; vi[t] = cand_idx[t];
  __syncthreads();
  unsigned b = vb[t], id = vi[t];
  int rank = 0;
  for (int u = 0; u < 512; ++u)
    rank += (vb[u] > b) || (vb[u] == b && vi[u] < id);
  ord[rank] = id;
}

// ------- gather selected relations + rel_mask + loss scalars (grid TOPK+2) -------
__global__ __launch_bounds__(256)
void gather_fin(const unsigned* __restrict__ ord, const float* __restrict__ ns2,
                const SelState* st, float* __restrict__ out)
{
  const int r = blockIdx.x, t = threadIdx.x;
  if (r < TOPK) {
    unsigned id = ord[r];
    int a = id >> 11, b = id & 2047;
    out[r * 256 + t] = ns2[a * 256 + t] + ns2[b * 256 + t];
  } else {
    const int half = r - TOPK;          // 0 or 1
    out[TOPK * H2D + half * 256 + t] = 0.0f;   // rel_mask all False
    if (half == 1 && t == 0) {
      double s   = st->labSum;
      double nn  = (double)NN * NN;
      double pw  = (nn - s + NN) / (s - NN + 0.01);
      double nrm = nn / (nn - s + NN);
      out[TOPK * H2D + TOPK + 0] = (float)(nrm * (pw * st->sum1 + st->sum0) / nn);
      out[TOPK * H2D + TOPK + 1] = (float)(0.5 * st->kldSum / nn);
    }
  }
}

} // namespace

extern "C" void kernel_launch(void* const* d_in, const int* in_sizes, int n_in,
                              void* d_out, int out_size, void* d_ws, size_t ws_size,
                              hipStream_t stream)
{
  (void)in_sizes; (void)n_in; (void)out_size; (void)ws_size;
  const float* ns_emb    = (const float*)d_in[0];
  const float* adj       = (const float*)d_in[1];
  const float* adj_prior = (const float*)d_in[2];
  const float* cond      = (const float*)d_in[3];
  const float* labels    = (const float*)d_in[4];
  const float* eps       = (const float*)d_in[5];
  const float* W_map     = (const float*)d_in[6];
  const float* Wb[2][7];
  for (int k = 0; k < 14; ++k) Wb[k / 7][k % 7] = (const float*)d_in[7 + k];
  float* out = (float*)d_out;

  // ---- workspace ----
  char* w = (char*)d_ws;
  SelState* st      = (SelState*)w;          w += 256;
  unsigned* rowTies = (unsigned*)w;          w += NN * 4;     // memset with st
  unsigned* cand_bits = (unsigned*)w;        w += TOPK * 4;
  unsigned* cand_idx  = (unsigned*)w;        w += TOPK * 4;
  unsigned* ord       = (unsigned*)w;        w += TOPK * 4;
  w = (char*)(((uintptr_t)w + 255) & ~(uintptr_t)255);
  int* ellCnt[2]; int* ellCol[2]; float* ellVal[2];
  for (int b = 0; b < 2; ++b) {
    ellCnt[b] = (int*)w;   w += NN * 4;
    ellCol[b] = (int*)w;   w += (size_t)NN * CAP * 4;
    ellVal[b] = (float*)w; w += (size_t)NN * CAP * 4;
  }
  const long long NNH1 = (long long)NN * H1D;   // 4 MB slot
  const long long LCH  = (long long)LCD * H1D;
  float* AR = (float*)w;  w += (size_t)(8 * NNH1 + 4 * LCH) * 4;   // 34 MB arena
  float* mulv[2];
  mulv[0] = (float*)w;    w += (size_t)NNH1 * 4;
  mulv[1] = (float*)w;    w += (size_t)NNH1 * 4;
  float* zb  = (float*)w; w += (size_t)NN * H2D * 4;
  float* ns2 = (float*)w; w += (size_t)NN * H2D * 4;

  // arena slots + lifetimes:
  //  A0,A1: S -> SCp1 -> H2p1 -> radj(lo)     A2,A3: H -> SCp2 -> H2p2 -> radj(hi)
  //  A4..A7: Qp1/Qp2 -> Op1/Op2 -> T2[0..1](A4,A5)
  float* A_[8];
  for (int i = 0; i < 8; ++i) A_[i] = AR + (long long)i * NNH1;
  float* KV = AR + 8 * NNH1;
  float* Kb[2] = { KV,           KV + LCH };
  float* Vb[2] = { KV + 2*LCH,   KV + 3*LCH };
  float* S[2]   = { A_[0], A_[1] };
  float* H[2]   = { A_[2], A_[3] };
  float* Qp1[2] = { A_[4], A_[5] }, *Qp2[2] = { A_[6], A_[7] };
  float* SCp1 = A_[0], *SCp2 = A_[2];                 // 4 slices x [2048,256] each (2 slots)
  float* Op1[2] = { A_[4], A_[5] }, *Op2[2] = { A_[6], A_[7] };
  float* H2p1[2] = { A_[0], A_[1] }, *H2p2[2] = { A_[2], A_[3] };
  float* T2[2]  = { A_[4], A_[5] };
  float* radj = A_[0];                                // 4 slots (16 MB)

  hipMemsetAsync(st, 0, 256 + NN * 4, stream);

  { // ELL build
    EB eb{};
    eb.adj[0] = adj; eb.adj[1] = adj_prior;
    for (int b = 0; b < 2; ++b) { eb.cnt[b]=ellCnt[b]; eb.col[b]=ellCol[b]; eb.val[b]=ellVal[b]; }
    build_ell<<<dim3(NN, 2), 64, 0, stream>>>(eb);
  }

  auto mkslot = [](const float* A, const float* A2, const float* B, float* C,
                   int lda, int ldb, int ldc, int nshift, int act, float scale) {
    Slot s; s.A=A; s.A2=A2; s.B=B; s.C=C; s.lda=lda; s.ldb=ldb; s.ldc=ldc;
    s.nshift=nshift; s.act=act; s.scale=scale; return s;
  };
  auto setz = [](Launch& P, std::initializer_list<int> ze) {
    int i = 0, last = 0;
    for (int v : ze) { P.zend[i++] = v; last = v; }
    for (; i < 8; ++i) P.zend[i] = last;
  };

  { // phase 1 (unsplit): S[2] leaky, K/V[4], ns2 leaky — grid 768
    Launch P{};
    P.s[0] = mkslot(ns_emb, 0, Wb[0][0], S[0], FIN, H1D, H1D, 3, 1, 1.f);
    P.s[1] = mkslot(ns_emb, 0, Wb[1][0], S[1], FIN, H1D, H1D, 3, 1, 1.f);
    P.s[2] = mkslot(cond,   0, Wb[0][2], Kb[0], FIN, H1D, H1D, 3, 0, 1.f);
    P.s[3] = mkslot(cond,   0, Wb[1][2], Kb[1], FIN, H1D, H1D, 3, 0, 1.f);
    P.s[4] = mkslot(cond,   0, Wb[0][3], Vb[0], FIN, H1D, H1D, 3, 0, 1.f);
    P.s[5] = mkslot(cond,   0, Wb[1][3], Vb[1], FIN, H1D, H1D, 3, 0, 1.f);
    P.s[6] = mkslot(ns_emb, 0, W_map,    ns2,  FIN, H2D, H2D, 2, 1, 1.f);
    setz(P, {256, 512, 544, 576, 608, 640, 768, 768});
    mega_gemm<0,0><<<dim3(768), 256, 0, stream>>>(P, FIN);
  }
  { // spmm1: H = leaky(adj @ S)
    SB sb{};
    for (int br = 0; br < 2; ++br) { sb.cnt[br]=ellCnt[br]; sb.col[br]=ellCol[br];
      sb.val[br]=ellVal[br]; sb.S[br]=S[br]; sb.S2[br]=0; sb.out[br]=H[br]; }
    sb.asum = 0;
    spmm_leaky<<<dim3(NN, 2), 256, 0, stream>>>(sb);
  }
  { // Q split-K=2: Qp_kh[br] = H[br][:,kh*256:] @ Wq[kh*256:,:] — grid 1024
    Launch P{};
    for (int br = 0; br < 2; ++br)
      for (int kh = 0; kh < 2; ++kh)
        P.s[br*2+kh] = mkslot(H[br] + kh*256, 0, Wb[br][1] + kh*256*H1D,
                              (kh ? Qp2 : Qp1)[br], H1D, H1D, H1D, 3, 0, 1.f);
    setz(P, {256, 512, 768, 1024});
    mega_gemm<0,0><<<dim3(1024), 256, 0, stream>>>(P, 256);
  }
  { // scores split-K=2, A = Qp1+Qp2 (ASUM): SCp_kh[z] — grid 1024
    Launch P{};
    for (int br = 0; br < 2; ++br)
      for (int hd = 0; hd < 2; ++hd)
        for (int kh = 0; kh < 2; ++kh) {
          int z = br*2 + hd;
          P.s[z*2+kh] = mkslot(Qp1[br] + hd*256 + kh*128, Qp2[br] + hd*256 + kh*128,
                               Kb[br] + hd*256 + kh*128,
                               (kh ? SCp2 : SCp1) + (long long)z*NNQ,
                               H1D, H1D, 256, 2, 0, 0.0625f);
        }
    setz(P, {128, 256, 384, 512, 640, 768, 896, 1024});
    mega_gemm<1,1><<<dim3(1024), 256, 0, stream>>>(P, 128);
  }
  softmax256<<<dim3(NN), 256, 0, stream>>>(SCp1, SCp2);   // merge partials + softmax
  { // attnV split-K=2: Op_kh = SC[:,kh*128:] @ V[kh*128:,:] — grid 1024
    Launch P{};
    for (int br = 0; br < 2; ++br)
      for (int hd = 0; hd < 2; ++hd)
        for (int kh = 0; kh < 2; ++kh) {
          int z = br*2 + hd;
          P.s[z*2+kh] = mkslot(SCp1 + (long long)z*NNQ + kh*128, 0,
                               Vb[br] + (long long)(kh*128)*H1D + hd*256,
                               (kh ? Op2 : Op1)[br] + hd*256,
                               256, H1D, H1D, 2, 0, 1.f);
        }
    setz(P, {128, 256, 384, 512, 640, 768, 896, 1024});
    mega_gemm<0,0><<<dim3(1024), 256, 0, stream>>>(P, 128);
  }
  { // H2 split-K=2, A = Op1+Op2 (ASUM) — grid 1024
    Launch P{};
    for (int br = 0; br < 2; ++br)
      for (int kh = 0; kh < 2; ++kh)
        P.s[br*2+kh] = mkslot(Op1[br] + kh*256, Op2[br] + kh*256,
                              Wb[br][4] + kh*256*H1D,
                              (kh ? H2p2 : H2p1)[br], H1D, H1D, H1D, 3, 0, 1.f);
    setz(P, {256, 512, 768, 1024});
    mega_gemm<0,1><<<dim3(1024), 256, 0, stream>>>(P, 256);
  }
  { // T2 (unsplit K=512), A = H2p1+H2p2 (ASUM), leaky — grid 512
    Launch P{};
    for (int br = 0; br < 2; ++br) {
      P.s[br*2+0] = mkslot(H2p1[br], H2p2[br], Wb[br][5], T2[br],       H1D, H2D, H1D, 2, 1, 1.f);
      P.s[br*2+1] = mkslot(H2p1[br], H2p2[br], Wb[br][6], T2[br] + H2D, H1D, H2D, H1D, 2, 1, 1.f);
    }
    setz(P, {128, 256, 384, 512});
    mega_gemm<0,1><<<dim3(512), 256, 0, stream>>>(P, H1D);
  }
  { // spmm2: mulv = leaky(adj @ T2)
    SB sb{};
    for (int br = 0; br < 2; ++br) { sb.cnt[br]=ellCnt[br]; sb.col[br]=ellCol[br];
      sb.val[br]=ellVal[br]; sb.S[br]=T2[br]; sb.S2[br]=0; sb.out[br]=mulv[br]; }
    sb.asum = 0;
    spmm_leaky<<<dim3(NN, 2), 256, 0, stream>>>(sb);
  }

  z_kld<<<dim3(NN), 256, 0, stream>>>(eps, mulv[0], mulv[1], zb, st);
  zzt_fused<<<dim3(32, 32), 256, 0, stream>>>(zb, labels, radj, st, rowTies);

  select_all<<<dim3(1), 1024, 0, stream>>>(radj, st, rowTies);
  collect_kernel<<<dim3(NN), 256, 0, stream>>>(radj, st, cand_bits, cand_idx);
  rank_sort<<<dim3(1), 512, 0, stream>>>(cand_bits, cand_idx, ord);
  gather_fin<<<dim3(TOPK + 2), 256, 0, stream>>>(ord, ns2, st, out);
}